// Round 1
// baseline (889.869 us; speedup 1.0000x reference)
//
#include <hip/hip_runtime.h>

#define H_ 768
#define W_ 1024
#define HW_ (H_ * W_)
#define NFRAMES 16
#define NPAIRS 15

struct Xform {
    float R[9];
    float t[3];
};

// Build per-frame rotation/translation from pose (tx,ty,tz,qx,qy,qz,qw),
// and zero the per-pair accumulators.
__global__ void prep_kernel(const float* __restrict__ pose,
                            Xform* __restrict__ xf,
                            float* __restrict__ sums,
                            unsigned* __restrict__ cnts) {
    int f = threadIdx.x;
    if (f < NFRAMES) {
        const float* p = pose + f * 7;
        float tx = p[0], ty = p[1], tz = p[2];
        float x = p[3], y = p[4], z = p[5], w = p[6];
        float n = sqrtf(x * x + y * y + z * z + w * w);
        x /= n; y /= n; z /= n; w /= n;
        Xform X;
        X.R[0] = 1.f - 2.f * (y * y + z * z);
        X.R[1] = 2.f * (x * y - z * w);
        X.R[2] = 2.f * (x * z + y * w);
        X.R[3] = 2.f * (x * y + z * w);
        X.R[4] = 1.f - 2.f * (x * x + z * z);
        X.R[5] = 2.f * (y * z - x * w);
        X.R[6] = 2.f * (x * z - y * w);
        X.R[7] = 2.f * (y * z + x * w);
        X.R[8] = 1.f - 2.f * (x * x + y * y);
        X.t[0] = tx; X.t[1] = ty; X.t[2] = tz;
        xf[f] = X;
    }
    if (f < NPAIRS) {
        sums[f] = 0.f;
        cnts[f] = 0u;
    }
}

// Fill z-buffers with 0xFFFFFFFF (unsigned-max sentinel; any positive float's
// bits are smaller, so atomicMin(uint) implements float-min for z > 0).
__global__ void init_bufs_kernel(uint4* __restrict__ bufs, int n4) {
    int i = blockIdx.x * blockDim.x + threadIdx.x;
    if (i < n4) bufs[i] = make_uint4(0xFFFFFFFFu, 0xFFFFFFFFu, 0xFFFFFFFFu, 0xFFFFFFFFu);
}

// For each source pixel of frame A (= pair index p), reproject into frame B
// (= p+1) and scatter-min the z into the pair's z-buffer.
__global__ void scatter_kernel(const float* __restrict__ pred,
                               const Xform* __restrict__ xf,
                               const float* __restrict__ Km,
                               unsigned* __restrict__ bufs,
                               int pair0, int npairs) {
    long idx = (long)blockIdx.x * blockDim.x + threadIdx.x;
    if (idx >= (long)npairs * HW_) return;
    int pl = (int)(idx / HW_);          // local pair (buffer) index
    int pix = (int)(idx - (long)pl * HW_);
    int p = pair0 + pl;                 // frame A index

    float d = pred[(size_t)p * HW_ + pix];
    if (d == 0.f) return;               // validA

    int v = pix / W_;
    int u = pix - v * W_;
    float fx = Km[0], cx = Km[2], fy = Km[4], cy = Km[5];

    // unproject (match reference op order: (u - cx) * d / fx)
    float x = ((float)u - cx) * d / fx;
    float y = ((float)v - cy) * d / fy;

    Xform XA = xf[p];
    Xform XB = xf[p + 1];

    // pw = RA * pc + tA
    float pwx = XA.R[0] * x + XA.R[1] * y + XA.R[2] * d + XA.t[0];
    float pwy = XA.R[3] * x + XA.R[4] * y + XA.R[5] * d + XA.t[1];
    float pwz = XA.R[6] * x + XA.R[7] * y + XA.R[8] * d + XA.t[2];

    // q = RB^T * (pw - tB)
    float mx = pwx - XB.t[0];
    float my = pwy - XB.t[1];
    float mz = pwz - XB.t[2];
    float q0 = XB.R[0] * mx + XB.R[3] * my + XB.R[6] * mz;
    float q1 = XB.R[1] * mx + XB.R[4] * my + XB.R[7] * mz;
    float z  = XB.R[2] * mx + XB.R[5] * my + XB.R[8] * mz;

    if (!(z > 0.f)) return;

    float u2 = fx * q0 / z + cx;
    float v2 = fy * q1 / z + cy;
    int ui = (int)rintf(u2);            // round half-to-even, matches jnp.round
    int vi = (int)rintf(v2);
    if (ui < 0 || ui >= W_ || vi < 0 || vi >= H_) return;

    atomicMin(&bufs[(size_t)pl * HW_ + (size_t)vi * W_ + ui], __float_as_uint(z));
}

// Per-pixel: hit pixels contribute (zbuf - depthB) to sum and 1 to cnt;
// non-hit pixels with depthB != 0 contribute 1 to cnt only.
__global__ void reduce_kernel(const float* __restrict__ pred,
                              const unsigned* __restrict__ bufs,
                              float* __restrict__ sums,
                              unsigned* __restrict__ cnts,
                              int pair0, int npairs) {
    long idx = (long)blockIdx.x * blockDim.x + threadIdx.x;
    int pl = (int)(idx / HW_);
    int pix = (int)(idx - (long)pl * HW_);
    int p = pair0 + pl;

    float s = 0.f;
    unsigned c = 0u;
    if (idx < (long)npairs * HW_) {
        unsigned b = bufs[(size_t)pl * HW_ + pix];
        float db = pred[(size_t)(p + 1) * HW_ + pix];
        if (b != 0xFFFFFFFFu) {
            s = __uint_as_float(b) - db;
            c = 1u;
        } else if (db != 0.f) {
            c = 1u;
        }
    }

    // wave64 butterfly reduce
    for (int off = 32; off > 0; off >>= 1) {
        s += __shfl_down(s, off);
        c += __shfl_down(c, off);
    }
    __shared__ float ls[4];
    __shared__ unsigned lc[4];
    int lane = threadIdx.x & 63;
    int wid = threadIdx.x >> 6;
    if (lane == 0) { ls[wid] = s; lc[wid] = c; }
    __syncthreads();
    if (threadIdx.x == 0) {
        float ts = ls[0] + ls[1] + ls[2] + ls[3];
        unsigned tc = lc[0] + lc[1] + lc[2] + lc[3];
        // HW_ divisible by 256 -> every block lies within one pair
        atomicAdd(&sums[p], ts);
        atomicAdd(&cnts[p], tc);
    }
}

__global__ void final_kernel(const float* __restrict__ sums,
                             const unsigned* __restrict__ cnts,
                             float* __restrict__ out) {
    if (threadIdx.x == 0 && blockIdx.x == 0) {
        float acc = 0.f;
        for (int pp = 0; pp < NPAIRS; ++pp) {
            unsigned c = cnts[pp];
            if (c < 1u) c = 1u;
            acc += sums[pp] / (float)c;
        }
        out[0] = acc;
    }
}

extern "C" void kernel_launch(void* const* d_in, const int* in_sizes, int n_in,
                              void* d_out, int out_size, void* d_ws, size_t ws_size,
                              hipStream_t stream) {
    const float* pred = (const float*)d_in[0];   // (16,1,768,1024) f32
    const float* pose = (const float*)d_in[1];   // (16,7) f32
    const float* Km   = (const float*)d_in[2];   // (3,3) f32
    float* out = (float*)d_out;
    char* ws = (char*)d_ws;

    size_t buf_bytes_all = (size_t)NPAIRS * HW_ * sizeof(unsigned);
    size_t tail_bytes = NFRAMES * sizeof(Xform) + NPAIRS * sizeof(float) + NPAIRS * sizeof(unsigned) + 256;
    bool pathA = ws_size >= buf_bytes_all + tail_bytes;
    int nbuf = pathA ? NPAIRS : 1;

    unsigned* bufs = (unsigned*)ws;
    Xform* xf = (Xform*)(ws + (size_t)nbuf * HW_ * sizeof(unsigned));
    float* sums = (float*)((char*)xf + NFRAMES * sizeof(Xform));
    unsigned* cnts = (unsigned*)((char*)sums + NPAIRS * sizeof(float));

    prep_kernel<<<1, 64, 0, stream>>>(pose, xf, sums, cnts);

    if (pathA) {
        int n4 = NPAIRS * HW_ / 4;
        init_bufs_kernel<<<(n4 + 255) / 256, 256, 0, stream>>>((uint4*)bufs, n4);
        long n = (long)NPAIRS * HW_;
        int blocks = (int)(n / 256);   // HW_ divisible by 256
        scatter_kernel<<<blocks, 256, 0, stream>>>(pred, xf, Km, bufs, 0, NPAIRS);
        reduce_kernel<<<blocks, 256, 0, stream>>>(pred, bufs, sums, cnts, 0, NPAIRS);
    } else {
        int n4 = HW_ / 4;
        int blocks = HW_ / 256;
        for (int p = 0; p < NPAIRS; ++p) {
            init_bufs_kernel<<<(n4 + 255) / 256, 256, 0, stream>>>((uint4*)bufs, n4);
            scatter_kernel<<<blocks, 256, 0, stream>>>(pred, xf, Km, bufs, p, 1);
            reduce_kernel<<<blocks, 256, 0, stream>>>(pred, bufs, sums, cnts, p, 1);
        }
    }

    final_kernel<<<1, 64, 0, stream>>>(sums, cnts, out);
}

// Round 6
// 343.190 us; speedup vs baseline: 2.5929x; 2.5929x over previous
//
#include <hip/hip_runtime.h>

#define H_ 768
#define W_ 1024
#define HW_ (H_ * W_)
#define NFRAMES 16
#define NPAIRS 15
#define RB_PER_PAIR 64              // reduce blocks per pair

struct Xform {
    float R[9];
    float t[3];
};

__global__ void prep_kernel(const float* __restrict__ pose,
                            Xform* __restrict__ xf,
                            float* __restrict__ sums,
                            unsigned* __restrict__ cnts) {
    int f = threadIdx.x;
    if (f < NFRAMES) {
        const float* p = pose + f * 7;
        float tx = p[0], ty = p[1], tz = p[2];
        float x = p[3], y = p[4], z = p[5], w = p[6];
        float n = sqrtf(x * x + y * y + z * z + w * w);
        x /= n; y /= n; z /= n; w /= n;
        Xform X;
        X.R[0] = 1.f - 2.f * (y * y + z * z);
        X.R[1] = 2.f * (x * y - z * w);
        X.R[2] = 2.f * (x * z + y * w);
        X.R[3] = 2.f * (x * y + z * w);
        X.R[4] = 1.f - 2.f * (x * x + z * z);
        X.R[5] = 2.f * (y * z - x * w);
        X.R[6] = 2.f * (x * z - y * w);
        X.R[7] = 2.f * (y * z + x * w);
        X.R[8] = 1.f - 2.f * (x * x + y * y);
        X.t[0] = tx; X.t[1] = ty; X.t[2] = tz;
        xf[f] = X;
    }
    if (f < NPAIRS) {
        sums[f] = 0.f;
        cnts[f] = 0u;
    }
}

// Fill z-buffers with 0xFFFFFFFF sentinel (unsigned-max; any positive float's
// bits are smaller, so atomicMin(uint) == float-min for z > 0).
__global__ void init_bufs_kernel(uint4* __restrict__ bufs, int n4) {
    int i = blockIdx.x * blockDim.x + threadIdx.x;
    if (i < n4) bufs[i] = make_uint4(0xFFFFFFFFu, 0xFFFFFFFFu, 0xFFFFFFFFu, 0xFFFFFFFFu);
}

// 4 pixels per thread (one float4 row-segment). Blocks are pair-uniform
// (HW_/4 divisible by 256), so Xform loads are scalar.
__global__ void scatter_kernel(const float* __restrict__ pred,
                               const Xform* __restrict__ xf,
                               const float* __restrict__ Km,
                               unsigned* __restrict__ bufs,
                               int pair0, int npairs) {
    int tid = blockIdx.x * blockDim.x + threadIdx.x;
    if (tid >= npairs * (HW_ / 4)) return;
    int pl = tid / (HW_ / 4);
    int pix0 = (tid - pl * (HW_ / 4)) * 4;
    int p = pair0 + pl;

    float4 d4 = *(const float4*)(pred + (size_t)p * HW_ + pix0);
    float dd[4] = {d4.x, d4.y, d4.z, d4.w};

    float fx = Km[0], cx = Km[2], fy = Km[4], cy = Km[5];
    Xform XA = xf[p];
    Xform XB = xf[p + 1];
    unsigned* buf = bufs + (size_t)pl * HW_;

    int v = pix0 >> 10;                 // W_ == 1024
    int u0 = pix0 & (W_ - 1);

#pragma unroll
    for (int k = 0; k < 4; ++k) {
        float d = dd[k];
        if (d == 0.f) continue;

        float x = ((float)(u0 + k) - cx) * d / fx;
        float y = ((float)v - cy) * d / fy;

        float pwx = XA.R[0] * x + XA.R[1] * y + XA.R[2] * d + XA.t[0];
        float pwy = XA.R[3] * x + XA.R[4] * y + XA.R[5] * d + XA.t[1];
        float pwz = XA.R[6] * x + XA.R[7] * y + XA.R[8] * d + XA.t[2];

        float mx = pwx - XB.t[0];
        float my = pwy - XB.t[1];
        float mz = pwz - XB.t[2];
        float q0 = XB.R[0] * mx + XB.R[3] * my + XB.R[6] * mz;
        float q1 = XB.R[1] * mx + XB.R[4] * my + XB.R[7] * mz;
        float z  = XB.R[2] * mx + XB.R[5] * my + XB.R[8] * mz;

        if (!(z > 0.f)) continue;

        float u2 = fx * q0 / z + cx;
        float v2 = fy * q1 / z + cy;
        int ui = (int)rintf(u2);
        int vi = (int)rintf(v2);
        if (ui < 0 || ui >= W_ || vi < 0 || vi >= H_) continue;

        atomicMin(&buf[(size_t)vi * W_ + ui], __float_as_uint(z));
    }
}

// Grid-stride reduce: RB_PER_PAIR blocks per pair, uint4/float4 loads,
// one atomicAdd pair per block (contention 64 per address, negligible).
__global__ void reduce_kernel(const float* __restrict__ pred,
                              const unsigned* __restrict__ bufs,
                              float* __restrict__ sums,
                              unsigned* __restrict__ cnts,
                              int pair0) {
    int pl = blockIdx.x / RB_PER_PAIR;
    int chunk = blockIdx.x - pl * RB_PER_PAIR;
    int p = pair0 + pl;

    const uint4* b4 = (const uint4*)(bufs + (size_t)pl * HW_);
    const float4* d4 = (const float4*)(pred + (size_t)(p + 1) * HW_);

    const int per_block = HW_ / 4 / RB_PER_PAIR;      // 3072 uint4
    const int iters = per_block / 256;                // 12
    int base = chunk * per_block + threadIdx.x;

    float s = 0.f;
    unsigned c = 0u;
#pragma unroll
    for (int it = 0; it < iters; ++it) {
        int i = base + it * 256;
        uint4 b = b4[i];
        float4 db = d4[i];
        {
            if (b.x != 0xFFFFFFFFu) { s += __uint_as_float(b.x) - db.x; ++c; }
            else if (db.x != 0.f) ++c;
            if (b.y != 0xFFFFFFFFu) { s += __uint_as_float(b.y) - db.y; ++c; }
            else if (db.y != 0.f) ++c;
            if (b.z != 0xFFFFFFFFu) { s += __uint_as_float(b.z) - db.z; ++c; }
            else if (db.z != 0.f) ++c;
            if (b.w != 0xFFFFFFFFu) { s += __uint_as_float(b.w) - db.w; ++c; }
            else if (db.w != 0.f) ++c;
        }
    }

    for (int off = 32; off > 0; off >>= 1) {
        s += __shfl_down(s, off);
        c += __shfl_down(c, off);
    }
    __shared__ float ls[4];
    __shared__ unsigned lc[4];
    int lane = threadIdx.x & 63;
    int wid = threadIdx.x >> 6;
    if (lane == 0) { ls[wid] = s; lc[wid] = c; }
    __syncthreads();
    if (threadIdx.x == 0) {
        atomicAdd(&sums[p], ls[0] + ls[1] + ls[2] + ls[3]);
        atomicAdd(&cnts[p], lc[0] + lc[1] + lc[2] + lc[3]);
    }
}

__global__ void final_kernel(const float* __restrict__ sums,
                             const unsigned* __restrict__ cnts,
                             float* __restrict__ out) {
    if (threadIdx.x == 0 && blockIdx.x == 0) {
        float acc = 0.f;
        for (int pp = 0; pp < NPAIRS; ++pp) {
            unsigned c = cnts[pp];
            if (c < 1u) c = 1u;
            acc += sums[pp] / (float)c;
        }
        out[0] = acc;
    }
}

extern "C" void kernel_launch(void* const* d_in, const int* in_sizes, int n_in,
                              void* d_out, int out_size, void* d_ws, size_t ws_size,
                              hipStream_t stream) {
    const float* pred = (const float*)d_in[0];   // (16,1,768,1024) f32
    const float* pose = (const float*)d_in[1];   // (16,7) f32
    const float* Km   = (const float*)d_in[2];   // (3,3) f32
    float* out = (float*)d_out;
    char* ws = (char*)d_ws;

    size_t buf_bytes_all = (size_t)NPAIRS * HW_ * sizeof(unsigned);
    size_t tail_bytes = NFRAMES * sizeof(Xform) + NPAIRS * sizeof(float) + NPAIRS * sizeof(unsigned) + 256;
    bool pathA = ws_size >= buf_bytes_all + tail_bytes;
    int nbuf = pathA ? NPAIRS : 1;

    unsigned* bufs = (unsigned*)ws;
    Xform* xf = (Xform*)(ws + (size_t)nbuf * HW_ * sizeof(unsigned));
    float* sums = (float*)((char*)xf + NFRAMES * sizeof(Xform));
    unsigned* cnts = (unsigned*)((char*)sums + NPAIRS * sizeof(float));

    prep_kernel<<<1, 64, 0, stream>>>(pose, xf, sums, cnts);

    if (pathA) {
        int n4 = NPAIRS * HW_ / 4;
        init_bufs_kernel<<<(n4 + 255) / 256, 256, 0, stream>>>((uint4*)bufs, n4);
        int sblocks = NPAIRS * (HW_ / 4) / 256;
        scatter_kernel<<<sblocks, 256, 0, stream>>>(pred, xf, Km, bufs, 0, NPAIRS);
        reduce_kernel<<<NPAIRS * RB_PER_PAIR, 256, 0, stream>>>(pred, bufs, sums, cnts, 0);
    } else {
        int n4 = HW_ / 4;
        for (int p = 0; p < NPAIRS; ++p) {
            init_bufs_kernel<<<(n4 + 255) / 256, 256, 0, stream>>>((uint4*)bufs, n4);
            scatter_kernel<<<HW_ / 4 / 256, 256, 0, stream>>>(pred, xf, Km, bufs, p, 1);
            reduce_kernel<<<RB_PER_PAIR, 256, 0, stream>>>(pred, bufs, sums, cnts, p);
        }
    }

    final_kernel<<<1, 64, 0, stream>>>(sums, cnts, out);
}

// Round 8
// 200.030 us; speedup vs baseline: 4.4487x; 1.7157x over previous
//
#include <hip/hip_runtime.h>

#define H_ 768
#define W_ 1024
#define HW_ (H_ * W_)
#define NFRAMES 16
#define NPAIRS 15
#define NB_ 96                      // bands per pair, 8 rows each
#define BAND_ROWS 8
#define BAND_PX (BAND_ROWS * W_)    // 8192
#define ROWS_PER_BLK 4
#define BLKS_PER_PAIR (H_ / ROWS_PER_BLK)   // 192

struct Xform {
    float R[9];
    float t[3];
};

// Deterministic projection: explicit __fmaf_rn everywhere so count/fill/zmin
// kernels produce BIT-IDENTICAL (vi,ui,z) for the same pixel (no codegen
// contraction freedom). Mul-feeding-div/add patterns are not contractible.
__device__ __forceinline__ bool project_px(
    float d, int u, int v,
    float fx, float fy, float cx, float cy,
    const Xform& XA, const Xform& XB,
    int& vi, int& ui, unsigned& zbits)
{
    if (d == 0.f) return false;                       // validA
    float x = ((float)u - cx) * d / fx;
    float y = ((float)v - cy) * d / fy;
    float pwx = __fmaf_rn(XA.R[0], x, __fmaf_rn(XA.R[1], y, __fmaf_rn(XA.R[2], d, XA.t[0])));
    float pwy = __fmaf_rn(XA.R[3], x, __fmaf_rn(XA.R[4], y, __fmaf_rn(XA.R[5], d, XA.t[1])));
    float pwz = __fmaf_rn(XA.R[6], x, __fmaf_rn(XA.R[7], y, __fmaf_rn(XA.R[8], d, XA.t[2])));
    float mx = pwx - XB.t[0];
    float my = pwy - XB.t[1];
    float mz = pwz - XB.t[2];
    float q0 = __fmaf_rn(XB.R[0], mx, __fmaf_rn(XB.R[3], my, XB.R[6] * mz));
    float q1 = __fmaf_rn(XB.R[1], mx, __fmaf_rn(XB.R[4], my, XB.R[7] * mz));
    float z  = __fmaf_rn(XB.R[2], mx, __fmaf_rn(XB.R[5], my, XB.R[8] * mz));
    if (!(z > 0.f)) return false;
    float tu = fx * q0;
    float tv = fy * q1;
    float u2 = tu / z + cx;
    float v2 = tv / z + cy;
    int uii = (int)rintf(u2);                         // round-half-even = jnp.round
    int vii = (int)rintf(v2);
    if (uii < 0 || uii >= W_ || vii < 0 || vii >= H_) return false;
    vi = vii; ui = uii; zbits = __float_as_uint(z);   // z>0 -> uint order == float order
    return true;
}

__global__ void prep_kernel(const float* __restrict__ pose,
                            Xform* __restrict__ xf,
                            unsigned* __restrict__ hist) {
    int t = threadIdx.x;
    if (t < NFRAMES) {
        const float* p = pose + t * 7;
        float tx = p[0], ty = p[1], tz = p[2];
        float x = p[3], y = p[4], z = p[5], w = p[6];
        float n = sqrtf(x * x + y * y + z * z + w * w);
        x /= n; y /= n; z /= n; w /= n;
        Xform X;
        X.R[0] = 1.f - 2.f * (y * y + z * z);
        X.R[1] = 2.f * (x * y - z * w);
        X.R[2] = 2.f * (x * z + y * w);
        X.R[3] = 2.f * (x * y + z * w);
        X.R[4] = 1.f - 2.f * (x * x + z * z);
        X.R[5] = 2.f * (y * z - x * w);
        X.R[6] = 2.f * (x * z - y * w);
        X.R[7] = 2.f * (y * z + x * w);
        X.R[8] = 1.f - 2.f * (x * x + y * y);
        X.t[0] = tx; X.t[1] = ty; X.t[2] = tz;
        xf[t] = X;
    }
    for (int i = t; i < NPAIRS * NB_; i += 256) hist[i] = 0u;
}

// Pass 1: per-band entry counts. Block = 4 source rows of one pair.
__global__ void count_kernel(const float* __restrict__ pred,
                             const Xform* __restrict__ xf,
                             const float* __restrict__ Km,
                             unsigned* __restrict__ hist, int pair0) {
    int pair = pair0 + blockIdx.x / BLKS_PER_PAIR;
    int rowblk = blockIdx.x % BLKS_PER_PAIR;
    int t = threadIdx.x;
    __shared__ unsigned cnt[NB_];
    if (t < NB_) cnt[t] = 0u;
    __syncthreads();
    float fx = Km[0], cx = Km[2], fy = Km[4], cy = Km[5];
    Xform XA = xf[pair], XB = xf[pair + 1];
    int row = rowblk * ROWS_PER_BLK + (t >> 6);
    int px0 = (t & 63) * 16;
    const float* src = pred + (size_t)pair * HW_ + row * W_ + px0;
#pragma unroll
    for (int k = 0; k < 4; ++k) {
        float4 d4 = *(const float4*)(src + 4 * k);
        float dd[4] = {d4.x, d4.y, d4.z, d4.w};
#pragma unroll
        for (int j = 0; j < 4; ++j) {
            int vi, ui; unsigned zb;
            if (project_px(dd[j], px0 + 4 * k + j, row, fx, fy, cx, cy, XA, XB, vi, ui, zb))
                atomicAdd(&cnt[vi >> 3], 1u);
        }
    }
    __syncthreads();
    if (t < NB_ && cnt[t]) atomicAdd(&hist[pair * NB_ + t], cnt[t]);
}

// Pass 2: exclusive scan of n band counts (relative to 0), init cursors.
__global__ void scan_kernel(const unsigned* __restrict__ hist,
                            unsigned* __restrict__ offsets,
                            unsigned* __restrict__ cursor,
                            int base, int n) {
    int t = threadIdx.x;
    __shared__ unsigned part[256];
    unsigned v[6];
    unsigned sum = 0;
#pragma unroll
    for (int j = 0; j < 6; ++j) {
        int i = t * 6 + j;
        v[j] = (i < n) ? hist[base + i] : 0u;
        sum += v[j];
    }
    part[t] = sum;
    __syncthreads();
    if (t == 0) {
        unsigned run = 0;
        for (int i = 0; i < 256; ++i) { unsigned tmp = part[i]; part[i] = run; run += tmp; }
        offsets[base + n] = run;
    }
    __syncthreads();
    unsigned off = part[t];
#pragma unroll
    for (int j = 0; j < 6; ++j) {
        int i = t * 6 + j;
        if (i < n) { offsets[base + i] = off; cursor[base + i] = off; off += v[j]; }
    }
}

// Pass 3: write source-pixel ids into per-band bins (counting sort).
__global__ void fill_kernel(const float* __restrict__ pred,
                            const Xform* __restrict__ xf,
                            const float* __restrict__ Km,
                            unsigned* __restrict__ cursor,
                            unsigned* __restrict__ bins, int pair0) {
    int pair = pair0 + blockIdx.x / BLKS_PER_PAIR;
    int rowblk = blockIdx.x % BLKS_PER_PAIR;
    int t = threadIdx.x;
    __shared__ unsigned cnt[NB_];
    __shared__ unsigned base[NB_];
    if (t < NB_) cnt[t] = 0u;
    __syncthreads();
    float fx = Km[0], cx = Km[2], fy = Km[4], cy = Km[5];
    Xform XA = xf[pair], XB = xf[pair + 1];
    int row = rowblk * ROWS_PER_BLK + (t >> 6);
    int px0 = (t & 63) * 16;
    const float* src = pred + (size_t)pair * HW_ + row * W_ + px0;
    unsigned pack[16];
#pragma unroll
    for (int k = 0; k < 4; ++k) {
        float4 d4 = *(const float4*)(src + 4 * k);
        float dd[4] = {d4.x, d4.y, d4.z, d4.w};
#pragma unroll
        for (int j = 0; j < 4; ++j) {
            int idx = 4 * k + j;
            pack[idx] = 0xFFFFFFFFu;
            int vi, ui; unsigned zb;
            if (project_px(dd[j], px0 + idx, row, fx, fy, cx, cy, XA, XB, vi, ui, zb)) {
                unsigned b = (unsigned)(vi >> 3);
                unsigned loc = atomicAdd(&cnt[b], 1u);   // local slot (<4096, fits 16b)
                pack[idx] = (b << 16) | loc;
            }
        }
    }
    __syncthreads();
    if (t < NB_ && cnt[t]) base[t] = atomicAdd(&cursor[pair * NB_ + t], cnt[t]);
    __syncthreads();
    int pixrow = row * W_ + px0;
#pragma unroll
    for (int idx = 0; idx < 16; ++idx) {
        unsigned pk = pack[idx];
        if (pk != 0xFFFFFFFFu)
            bins[base[pk >> 16] + (pk & 0xFFFFu)] = (unsigned)(pixrow + idx);
    }
}

// Pass 4: per-band LDS z-buffer (8x1024) + fused masked reduce -> partials.
__global__ void zmin_kernel(const float* __restrict__ pred,
                            const Xform* __restrict__ xf,
                            const float* __restrict__ Km,
                            const unsigned* __restrict__ offsets,
                            const unsigned* __restrict__ bins,
                            float* __restrict__ partial_s,
                            unsigned* __restrict__ partial_c, int pair0) {
    int gband = pair0 * NB_ + blockIdx.x;
    int pair = gband / NB_;
    int band = gband % NB_;
    int t = threadIdx.x;
    __shared__ unsigned zb[BAND_PX];
#pragma unroll
    for (int k = 0; k < BAND_PX / 256; ++k) zb[k * 256 + t] = 0xFFFFFFFFu;
    __syncthreads();
    float fx = Km[0], cx = Km[2], fy = Km[4], cy = Km[5];
    Xform XA = xf[pair], XB = xf[pair + 1];
    unsigned off0 = offsets[gband], off1 = offsets[gband + 1];
    const float* predA = pred + (size_t)pair * HW_;
    for (unsigned i = off0 + t; i < off1; i += 256) {
        unsigned pix = bins[i];
        float d = predA[pix];
        int vi, ui; unsigned zbits;
        if (project_px(d, (int)(pix & (W_ - 1)), (int)(pix >> 10),
                       fx, fy, cx, cy, XA, XB, vi, ui, zbits))
            atomicMin(&zb[((vi & (BAND_ROWS - 1)) << 10) | ui], zbits);
    }
    __syncthreads();
    const float4* pb4 = (const float4*)(pred + (size_t)(pair + 1) * HW_ + (size_t)band * BAND_PX);
    const uint4* zb4 = (const uint4*)zb;
    float s = 0.f; unsigned c = 0u;
#pragma unroll
    for (int k = 0; k < BAND_PX / 1024; ++k) {
        int i4 = k * 256 + t;
        uint4 b = zb4[i4];
        float4 db = pb4[i4];
        if (b.x != 0xFFFFFFFFu) { s += __uint_as_float(b.x) - db.x; ++c; } else if (db.x != 0.f) ++c;
        if (b.y != 0xFFFFFFFFu) { s += __uint_as_float(b.y) - db.y; ++c; } else if (db.y != 0.f) ++c;
        if (b.z != 0xFFFFFFFFu) { s += __uint_as_float(b.z) - db.z; ++c; } else if (db.z != 0.f) ++c;
        if (b.w != 0xFFFFFFFFu) { s += __uint_as_float(b.w) - db.w; ++c; } else if (db.w != 0.f) ++c;
    }
    for (int off = 32; off > 0; off >>= 1) {
        s += __shfl_down(s, off);
        c += __shfl_down(c, off);
    }
    __shared__ float ls[4];
    __shared__ unsigned lc[4];
    int lane = t & 63, wid = t >> 6;
    if (lane == 0) { ls[wid] = s; lc[wid] = c; }
    __syncthreads();
    if (t == 0) {
        partial_s[gband] = ls[0] + ls[1] + ls[2] + ls[3];
        partial_c[gband] = lc[0] + lc[1] + lc[2] + lc[3];
    }
}

__global__ void final_kernel(const float* __restrict__ partial_s,
                             const unsigned* __restrict__ partial_c,
                             float* __restrict__ out) {
    int t = threadIdx.x;
    __shared__ float ps[NPAIRS];
    __shared__ unsigned pc[NPAIRS];
    int pair = t >> 4, sub = t & 15;
    float s = 0.f; unsigned c = 0u;
    if (t < NPAIRS * 16) {
#pragma unroll
        for (int j = 0; j < 6; ++j) {
            int g = pair * NB_ + sub + j * 16;
            s += partial_s[g];
            c += partial_c[g];
        }
        for (int m = 1; m < 16; m <<= 1) { s += __shfl_xor(s, m); c += __shfl_xor(c, m); }
        if (sub == 0) { ps[pair] = s; pc[pair] = c; }
    }
    __syncthreads();
    if (t == 0) {
        float acc = 0.f;
        for (int p = 0; p < NPAIRS; ++p) {
            unsigned cc = pc[p];
            if (cc < 1u) cc = 1u;
            acc += ps[p] / (float)cc;
        }
        out[0] = acc;
    }
}

extern "C" void kernel_launch(void* const* d_in, const int* in_sizes, int n_in,
                              void* d_out, int out_size, void* d_ws, size_t ws_size,
                              hipStream_t stream) {
    const float* pred = (const float*)d_in[0];   // (16,1,768,1024) f32
    const float* pose = (const float*)d_in[1];   // (16,7) f32
    const float* Km   = (const float*)d_in[2];   // (3,3) f32
    float* out = (float*)d_out;
    char* ws = (char*)d_ws;

    // ws layout: hist[1440] | offsets[1441] | cursor[1440] | partial_c[1440]
    //            | partial_s[1440] | (align64) xf[16] | (align64) bins[...]
    unsigned* hist      = (unsigned*)ws;
    unsigned* offsets   = hist + NPAIRS * NB_;
    unsigned* cursor    = offsets + NPAIRS * NB_ + 1;
    unsigned* partial_c = cursor + NPAIRS * NB_;
    float*    partial_s = (float*)(partial_c + NPAIRS * NB_);
    Xform*    xf        = (Xform*)(ws + 28864);
    unsigned* bins      = (unsigned*)(ws + 29696);

    size_t binsA = (size_t)NPAIRS * HW_ * sizeof(unsigned);
    bool pathA = ws_size >= 29696 + binsA;

    prep_kernel<<<1, 256, 0, stream>>>(pose, xf, hist);

    if (pathA) {
        count_kernel<<<NPAIRS * BLKS_PER_PAIR, 256, 0, stream>>>(pred, xf, Km, hist, 0);
        scan_kernel<<<1, 256, 0, stream>>>(hist, offsets, cursor, 0, NPAIRS * NB_);
        fill_kernel<<<NPAIRS * BLKS_PER_PAIR, 256, 0, stream>>>(pred, xf, Km, cursor, bins, 0);
        zmin_kernel<<<NPAIRS * NB_, 256, 0, stream>>>(pred, xf, Km, offsets, bins,
                                                      partial_s, partial_c, 0);
    } else {
        for (int p = 0; p < NPAIRS; ++p) {
            count_kernel<<<BLKS_PER_PAIR, 256, 0, stream>>>(pred, xf, Km, hist, p);
            scan_kernel<<<1, 256, 0, stream>>>(hist, offsets, cursor, p * NB_, NB_);
            fill_kernel<<<BLKS_PER_PAIR, 256, 0, stream>>>(pred, xf, Km, cursor, bins, p);
            zmin_kernel<<<NB_, 256, 0, stream>>>(pred, xf, Km, offsets, bins,
                                                 partial_s, partial_c, p);
        }
    }

    final_kernel<<<1, 256, 0, stream>>>(partial_s, partial_c, out);
}

// Round 9
// 173.340 us; speedup vs baseline: 5.1337x; 1.1540x over previous
//
#include <hip/hip_runtime.h>

#define H_ 768
#define W_ 1024
#define HW_ (H_ * W_)
#define NFRAMES 16
#define NPAIRS 15
#define NB_ 96                      // bands per pair, 8 rows each
#define BAND_ROWS 8
#define BAND_PX (BAND_ROWS * W_)    // 8192
#define ROWS_PER_BLK 4
#define BLKS_PER_PAIR (H_ / ROWS_PER_BLK)   // 192
#define MAXSEG BLKS_PER_PAIR        // worst case: every row-block feeds a band
#define NBANDS_ALL (NPAIRS * NB_)   // 1440

struct Xform {
    float R[9];
    float t[3];
};

// Projection happens in exactly ONE kernel (fill), so no cross-kernel
// bit-determinism is needed. Entry = (zq19 << 13) | slot13 where
// zq = (float_bits(z) + 0x1000) >> 13 (round-to-nearest, monotone in z),
// slot = ((vi&7)<<10) | ui. Positive-float bits >> 13 always fit 19 bits.
__device__ __forceinline__ bool project_px(
    float d, int u, int v,
    float fx, float fy, float cx, float cy,
    const Xform& XA, const Xform& XB,
    int& vi, int& ui, unsigned& zbits)
{
    if (d == 0.f) return false;                       // validA
    float x = ((float)u - cx) * d / fx;
    float y = ((float)v - cy) * d / fy;
    float pwx = __fmaf_rn(XA.R[0], x, __fmaf_rn(XA.R[1], y, __fmaf_rn(XA.R[2], d, XA.t[0])));
    float pwy = __fmaf_rn(XA.R[3], x, __fmaf_rn(XA.R[4], y, __fmaf_rn(XA.R[5], d, XA.t[1])));
    float pwz = __fmaf_rn(XA.R[6], x, __fmaf_rn(XA.R[7], y, __fmaf_rn(XA.R[8], d, XA.t[2])));
    float mx = pwx - XB.t[0];
    float my = pwy - XB.t[1];
    float mz = pwz - XB.t[2];
    float q0 = __fmaf_rn(XB.R[0], mx, __fmaf_rn(XB.R[3], my, XB.R[6] * mz));
    float q1 = __fmaf_rn(XB.R[1], mx, __fmaf_rn(XB.R[4], my, XB.R[7] * mz));
    float z  = __fmaf_rn(XB.R[2], mx, __fmaf_rn(XB.R[5], my, XB.R[8] * mz));
    if (!(z > 0.f)) return false;
    float u2 = fx * q0 / z + cx;
    float v2 = fy * q1 / z + cy;
    int uii = (int)rintf(u2);                         // round-half-even = jnp.round
    int vii = (int)rintf(v2);
    if (uii < 0 || uii >= W_ || vii < 0 || vii >= H_) return false;
    vi = vii; ui = uii; zbits = __float_as_uint(z);
    return true;
}

__global__ void prep_kernel(const float* __restrict__ pose,
                            Xform* __restrict__ xf,
                            unsigned* __restrict__ seg_cnt,
                            unsigned* __restrict__ alloc) {
    int t = threadIdx.x;
    if (t < NFRAMES) {
        const float* p = pose + t * 7;
        float tx = p[0], ty = p[1], tz = p[2];
        float x = p[3], y = p[4], z = p[5], w = p[6];
        float n = sqrtf(x * x + y * y + z * z + w * w);
        x /= n; y /= n; z /= n; w /= n;
        Xform X;
        X.R[0] = 1.f - 2.f * (y * y + z * z);
        X.R[1] = 2.f * (x * y - z * w);
        X.R[2] = 2.f * (x * z + y * w);
        X.R[3] = 2.f * (x * y + z * w);
        X.R[4] = 1.f - 2.f * (x * x + z * z);
        X.R[5] = 2.f * (y * z - x * w);
        X.R[6] = 2.f * (x * z - y * w);
        X.R[7] = 2.f * (y * z + x * w);
        X.R[8] = 1.f - 2.f * (x * x + y * y);
        X.t[0] = tx; X.t[1] = ty; X.t[2] = tz;
        xf[t] = X;
    }
    for (int i = t; i < NBANDS_ALL; i += 256) seg_cnt[i] = 0u;
    if (t == 0) alloc[0] = 0u;
}

__global__ void reset_alloc_kernel(unsigned* __restrict__ alloc) {
    alloc[0] = 0u;
}

// Single projection pass: bin entries (zq|slot) into per-band chunks
// reserved from a global bump allocator; record segment descriptors.
__global__ void fill_kernel(const float* __restrict__ pred,
                            const Xform* __restrict__ xf,
                            const float* __restrict__ Km,
                            unsigned* __restrict__ alloc,
                            unsigned* __restrict__ seg_cnt,
                            uint2* __restrict__ seg,
                            unsigned* __restrict__ bins, int pair0) {
    int pair = pair0 + blockIdx.x / BLKS_PER_PAIR;
    int rowblk = blockIdx.x % BLKS_PER_PAIR;
    int t = threadIdx.x;
    __shared__ unsigned cnt[NB_];
    __shared__ unsigned basev[NB_];
    __shared__ unsigned chunk_base;
    if (t < NB_) cnt[t] = 0u;
    __syncthreads();

    float fx = Km[0], cx = Km[2], fy = Km[4], cy = Km[5];
    Xform XA = xf[pair], XB = xf[pair + 1];
    int row = rowblk * ROWS_PER_BLK + (t >> 6);
    int px0 = (t & 63) * 16;
    const float* src = pred + (size_t)pair * HW_ + row * W_ + px0;

    unsigned entry[16];
    unsigned pk[16];
#pragma unroll
    for (int k = 0; k < 4; ++k) {
        float4 d4 = *(const float4*)(src + 4 * k);
        float dd[4] = {d4.x, d4.y, d4.z, d4.w};
#pragma unroll
        for (int j = 0; j < 4; ++j) {
            int idx = 4 * k + j;
            pk[idx] = 0xFFFFFFFFu;
            int vi, ui; unsigned zbits;
            if (project_px(dd[j], px0 + idx, row, fx, fy, cx, cy, XA, XB, vi, ui, zbits)) {
                unsigned band = (unsigned)(vi >> 3);
                unsigned slot = (((unsigned)vi & 7u) << 10) | (unsigned)ui;
                unsigned zq = (zbits + 0x1000u) >> 13;          // 19-bit monotone key
                entry[idx] = (zq << 13) | slot;
                unsigned loc = atomicAdd(&cnt[band], 1u);       // < 4096, fits 16b
                pk[idx] = (band << 16) | loc;
            }
        }
    }
    __syncthreads();
    if (t == 0) {
        unsigned run = 0;
        for (int i = 0; i < NB_; ++i) { unsigned c = cnt[i]; basev[i] = run; run += c; }
        chunk_base = atomicAdd(alloc, run);
    }
    __syncthreads();
    if (t < NB_ && cnt[t]) {
        unsigned b0 = chunk_base + basev[t];
        basev[t] = b0;                                          // absolute
        unsigned gb = (unsigned)(pair * NB_ + t);
        unsigned si = atomicAdd(&seg_cnt[gb], 1u);
        seg[(size_t)gb * MAXSEG + si] = make_uint2(b0, cnt[t]);
    }
    __syncthreads();
#pragma unroll
    for (int idx = 0; idx < 16; ++idx) {
        unsigned p = pk[idx];
        if (p != 0xFFFFFFFFu)
            bins[basev[p >> 16] + (p & 0xFFFFu)] = entry[idx];
    }
}

// Per-band LDS z-buffer from self-describing entries + fused masked reduce.
__global__ void zmin_kernel(const float* __restrict__ pred,
                            const unsigned* __restrict__ seg_cnt,
                            const uint2* __restrict__ seg,
                            const unsigned* __restrict__ bins,
                            float* __restrict__ partial_s,
                            unsigned* __restrict__ partial_c, int pair0) {
    int gband = pair0 * NB_ + blockIdx.x;
    int pair = gband / NB_;
    int band = gband % NB_;
    int t = threadIdx.x;
    __shared__ unsigned zb[BAND_PX];
#pragma unroll
    for (int k = 0; k < BAND_PX / 256; ++k) zb[k * 256 + t] = 0xFFFFFFFFu;
    __syncthreads();

    unsigned ns = seg_cnt[gband];
    const uint2* sgs = seg + (size_t)gband * MAXSEG;
    for (unsigned j = 0; j < ns; ++j) {
        uint2 sg = sgs[j];
        for (unsigned i = sg.x + t; i < sg.x + sg.y; i += 256) {
            unsigned e = bins[i];
            atomicMin(&zb[e & 8191u], e >> 13);
        }
    }
    __syncthreads();

    const float4* pb4 = (const float4*)(pred + (size_t)(pair + 1) * HW_ + (size_t)band * BAND_PX);
    const uint4* zb4 = (const uint4*)zb;
    float s = 0.f; unsigned c = 0u;
#pragma unroll
    for (int k = 0; k < BAND_PX / 1024; ++k) {
        int i4 = k * 256 + t;
        uint4 b = zb4[i4];
        float4 db = pb4[i4];
        if (b.x != 0xFFFFFFFFu) { s += __uint_as_float(b.x << 13) - db.x; ++c; } else if (db.x != 0.f) ++c;
        if (b.y != 0xFFFFFFFFu) { s += __uint_as_float(b.y << 13) - db.y; ++c; } else if (db.y != 0.f) ++c;
        if (b.z != 0xFFFFFFFFu) { s += __uint_as_float(b.z << 13) - db.z; ++c; } else if (db.z != 0.f) ++c;
        if (b.w != 0xFFFFFFFFu) { s += __uint_as_float(b.w << 13) - db.w; ++c; } else if (db.w != 0.f) ++c;
    }
    for (int off = 32; off > 0; off >>= 1) {
        s += __shfl_down(s, off);
        c += __shfl_down(c, off);
    }
    __shared__ float ls[4];
    __shared__ unsigned lc[4];
    int lane = t & 63, wid = t >> 6;
    if (lane == 0) { ls[wid] = s; lc[wid] = c; }
    __syncthreads();
    if (t == 0) {
        partial_s[gband] = ls[0] + ls[1] + ls[2] + ls[3];
        partial_c[gband] = lc[0] + lc[1] + lc[2] + lc[3];
    }
}

__global__ void final_kernel(const float* __restrict__ partial_s,
                             const unsigned* __restrict__ partial_c,
                             float* __restrict__ out) {
    int t = threadIdx.x;
    __shared__ float ps[NPAIRS];
    __shared__ unsigned pc[NPAIRS];
    int pair = t >> 4, sub = t & 15;
    float s = 0.f; unsigned c = 0u;
    if (t < NPAIRS * 16) {
#pragma unroll
        for (int j = 0; j < 6; ++j) {
            int g = pair * NB_ + sub + j * 16;
            s += partial_s[g];
            c += partial_c[g];
        }
        for (int m = 1; m < 16; m <<= 1) { s += __shfl_xor(s, m); c += __shfl_xor(c, m); }
        if (sub == 0) { ps[pair] = s; pc[pair] = c; }
    }
    __syncthreads();
    if (t == 0) {
        float acc = 0.f;
        for (int p = 0; p < NPAIRS; ++p) {
            unsigned cc = pc[p];
            if (cc < 1u) cc = 1u;
            acc += ps[p] / (float)cc;
        }
        out[0] = acc;
    }
}

extern "C" void kernel_launch(void* const* d_in, const int* in_sizes, int n_in,
                              void* d_out, int out_size, void* d_ws, size_t ws_size,
                              hipStream_t stream) {
    const float* pred = (const float*)d_in[0];   // (16,1,768,1024) f32
    const float* pose = (const float*)d_in[1];   // (16,7) f32
    const float* Km   = (const float*)d_in[2];   // (3,3) f32
    float* out = (float*)d_out;
    char* ws = (char*)d_ws;

    // ws layout (bytes):
    //     0: seg_cnt[1440]            (5760)
    //  5760: alloc[1]                 (4)
    //  5764: partial_c[1440]          (5760)
    // 11524: partial_s[1440]          (5760)  -> ends 17284
    // 17296: xf[16]                   (768)   -> ends 18064 (16-aligned)
    // 18064: seg[1440*192] uint2      (2211840) -> ends 2229904
    // 2229904: bins                   (pathA: 15*HW*4 ; pathB: HW*4)
    unsigned* seg_cnt   = (unsigned*)ws;
    unsigned* alloc     = (unsigned*)(ws + 5760);
    unsigned* partial_c = (unsigned*)(ws + 5764);
    float*    partial_s = (float*)(ws + 11524);
    Xform*    xf        = (Xform*)(ws + 17296);
    uint2*    seg       = (uint2*)(ws + 18064);
    unsigned* bins      = (unsigned*)(ws + 2229904);

    size_t needA = 2229904 + (size_t)NPAIRS * HW_ * sizeof(unsigned);
    bool pathA = ws_size >= needA;

    prep_kernel<<<1, 256, 0, stream>>>(pose, xf, seg_cnt, alloc);

    if (pathA) {
        fill_kernel<<<NPAIRS * BLKS_PER_PAIR, 256, 0, stream>>>(pred, xf, Km, alloc,
                                                                seg_cnt, seg, bins, 0);
        zmin_kernel<<<NPAIRS * NB_, 256, 0, stream>>>(pred, seg_cnt, seg, bins,
                                                      partial_s, partial_c, 0);
    } else {
        for (int p = 0; p < NPAIRS; ++p) {
            reset_alloc_kernel<<<1, 1, 0, stream>>>(alloc);
            fill_kernel<<<BLKS_PER_PAIR, 256, 0, stream>>>(pred, xf, Km, alloc,
                                                           seg_cnt, seg, bins, p);
            zmin_kernel<<<NB_, 256, 0, stream>>>(pred, seg_cnt, seg, bins,
                                                 partial_s, partial_c, p);
        }
    }

    final_kernel<<<1, 256, 0, stream>>>(partial_s, partial_c, out);
}